// Round 27
// baseline (28.953 us; speedup 1.0000x reference)
//
#include <hip/hip_runtime.h>

// ---------------------------------------------------------------------------
// FFT_Conv_Layer == 3x3 "same" spatial conv with flipped REAL filter plane.
//
// Ladder: R20 20.91 | R25 18.53 (champion: single dispatch, coalesced wf
// gather into LDS, 4-row quads, 32x64 wave tile, A+B from LDS).
// Bottom-up: stage ~2.5-4 + K 4.3 (LDS: 108 b128/wave) + store 2.6 ~= 10-12
// vs 18.5 measured. All cheap retile/pipeline variants INCREASE LDS reads
// (tile symmetry) -> buy the measurement instead.
// R26 DIAGNOSTIC (resubmitted after container failure): R25 with
// [acc+K+store] repeated 4x (unroll-1, per-rep barrier, identical stores).
// dV = (dur-18.5)/3 = marginal K+store.
//   dV ~ 7  -> stage+ramp ~ 11.6us is the sink -> staging latency next.
//   dV >= 8.5 -> K-loop dependency stalls -> pre-issue LDS reads next.
// Also puts conv_one into rocprof top-5 (MfmaUtil/conflicts visible).
// ---------------------------------------------------------------------------

typedef _Float16 f16x8 __attribute__((ext_vector_type(8)));
typedef float    f32x4 __attribute__((ext_vector_type(4)));

#define NB 16
#define NC 64
#define NH 64
#define NW 64
#define CHUNKS 528                 // 66 xp positions * 8 channel-chunks per slab
#define SLAB_BYTES (CHUNKS * 16)   // 8448 B per image row slab
#define IMG_LDS (6 * SLAB_BYTES)   // 50,688 B
#define WF_HALFS (9 * 2 * 4 * 64 * 8)  // 36,864 halfs = 73,728 B = 4608 chunks
#define REPS 4

__global__ __launch_bounds__(512, 1) void conv_one(const float* __restrict__ imgs,
                                                   const float* __restrict__ filts,
                                                   float* __restrict__ out) {
    __shared__ char lds[IMG_LDS + WF_HALFS * 2];   // 124,416 B
    char* wfl = lds + IMG_LDS;
    const int bid = blockIdx.x;
    const int swz = ((bid & 7) << 5) | (bid >> 3);   // bijective: 256 = 8*32
    const int b   = swz >> 4;
    const int y0  = (swz & 15) << 2;     // first of 4 output rows
    const int tid = threadIdx.x;
    const int w   = tid >> 6;            // wave 0..7
    const int l   = tid & 63;
    const int h   = l >> 4;              // k-chunk lane group
    const int r   = l & 15;              // A-row / B-col within fragment

    // ---- pads: 6 slabs x 16 chunks (xp = 0, 65) ----
    if (tid < 96) {
        const int sl  = tid >> 4;
        const int rem = tid & 15;
        const int ci  = rem >> 1;
        const int xp2 = (rem & 1) ? 65 : 0;
        const int c2  = xp2 * 8 + (ci ^ (xp2 & 7));
        f16x8 z;
        #pragma unroll
        for (int k = 0; k < 8; ++k) z[k] = (_Float16)0.f;
        *reinterpret_cast<f16x8*>(lds + sl * SLAB_BYTES + c2 * 16) = z;
    }

    // ---- image: stage 6 slabs (rows y0-1 .. y0+4), 48 jobs over 8 waves ----
    #pragma unroll
    for (int j = 0; j < 6; ++j) {
        const int job = w + j * 8;
        const int sl  = job >> 3;
        const int ci  = job & 7;
        const int yy  = y0 - 1 + sl;
        float fr[8];
        if ((unsigned)yy < (unsigned)NH) {
            const float* src = imgs + (((size_t)(b * NC + ci * 8)) * NH + yy) * NW + l;
            #pragma unroll
            for (int k = 0; k < 8; ++k) fr[k] = src[(size_t)k * NH * NW];
        } else {
            #pragma unroll
            for (int k = 0; k < 8; ++k) fr[k] = 0.f;
        }
        f16x8 v;
        #pragma unroll
        for (int k = 0; k < 8; ++k) v[k] = (_Float16)fr[k];
        const int xp = l + 1;
        const int chunk = xp * 8 + (ci ^ (xp & 7));
        *reinterpret_cast<f16x8*>(lds + sl * SLAB_BYTES + chunk * 16) = v;
    }

    // ---- wf: coalesced gather + LDS scatter (72 entries/thread) ----
    {
        const float2* filts2 = reinterpret_cast<const float2*>(filts);
        _Float16* wfh = reinterpret_cast<_Float16*>(wfl);
        #pragma unroll
        for (int k = 0; k < 72; ++k) {
            const int f = tid + k * 512;         // entry = i*576 + o*9 + t
            const float v = filts2[f].x;         // real plane
            const int i   = f / 576;
            const int rem = f - i * 576;
            const int o   = rem / 9;
            const int t   = rem - o * 9;
            const int kc = i >> 5, hh = (i >> 3) & 3, e = i & 7;
            const int n  = o >> 4,  rr = o & 15;
            const int c  = ((t * 2 + kc) * 4 + n) * 64 + hh * 16 + rr;
            wfh[c * 8 + e] = (_Float16)v;
        }
    }

    const int row = w >> 1;              // output row within quad (0..3)
    const int xh  = w & 1;               // x half (0..1)
    const int y   = y0 + row;

    #pragma unroll 1
    for (int rep = 0; rep < REPS; ++rep) {
        __syncthreads();                 // rep 0: phase-A barrier; others: CSE fence

        f32x4 acc[2][4];
        #pragma unroll
        for (int m = 0; m < 2; ++m)
            #pragma unroll
            for (int n = 0; n < 4; ++n)
                acc[m][n] = f32x4{0.f, 0.f, 0.f, 0.f};

        #pragma unroll
        for (int ky = 0; ky < 3; ++ky) {
            const char* slab = lds + (row + 2 - ky) * SLAB_BYTES;   // sl in 0..5
            #pragma unroll
            for (int kx = 0; kx < 3; ++kx) {
                const int t = ky * 3 + kx;
                const char* wt = wfl + (size_t)t * 8192;   // 512 chunks * 16B per tap
                #pragma unroll
                for (int kc = 0; kc < 2; ++kc) {
                    f16x8 a[2], bb[4];
                    #pragma unroll
                    for (int m = 0; m < 2; ++m) {
                        const int xp = xh * 32 + m * 16 + r + 2 - kx;  // 0..65
                        const int chunk = xp * 8 + (((kc << 2) + h) ^ (xp & 7));
                        a[m] = *reinterpret_cast<const f16x8*>(slab + chunk * 16);
                    }
                    #pragma unroll
                    for (int n = 0; n < 4; ++n)
                        bb[n] = *reinterpret_cast<const f16x8*>(
                            wt + (size_t)(kc * 4 + n) * 1024 + l * 16);
                    #pragma unroll
                    for (int m = 0; m < 2; ++m)
                        #pragma unroll
                        for (int n = 0; n < 4; ++n)
                            acc[m][n] = __builtin_amdgcn_mfma_f32_16x16x32_f16(a[m], bb[n], acc[m][n], 0, 0, 0);
                }
            }
        }

        #pragma unroll
        for (int m = 0; m < 2; ++m) {
            const int x0 = xh * 32 + m * 16 + h * 4;
            #pragma unroll
            for (int n = 0; n < 4; ++n) {
                const int o = n * 16 + r;
                *reinterpret_cast<f32x4*>(out + (((size_t)(b * 64 + o) * 64 + y) * 64) + x0) = acc[m][n];
            }
        }
    }
}

extern "C" void kernel_launch(void* const* d_in, const int* in_sizes, int n_in,
                              void* d_out, int out_size, void* d_ws, size_t ws_size,
                              hipStream_t stream) {
    const float* imgs  = (const float*)d_in[0];   // [16][64][64][64] f32
    const float* filts = (const float*)d_in[1];   // [1][64][64][3][3][2] f32
    float* out = (float*)d_out;                   // [16][64][64][64] f32
    (void)d_ws; (void)ws_size;                    // no workspace needed

    hipLaunchKernelGGL(conv_one, dim3(256), dim3(512), 0, stream, imgs, filts, out);
}

// Round 31
// 19.548 us; speedup vs baseline: 1.4812x; 1.4812x over previous
//
#include <hip/hip_runtime.h>

// ---------------------------------------------------------------------------
// FFT_Conv_Layer == 3x3 "same" spatial conv with flipped REAL filter plane.
//
// Ladder: R20 20.91 | R25 18.53 | R27 diag: marginal [acc+K+store] = 3.47us
// => phase A (stage+gather) + ramp ~= 15us is the sink. The wf gather's
// per-entry decode (~23 VALU x 72: two magic-mul divisions + extracts) +
// 72 ds_write_u16 scatter is the biggest phase-A instruction block.
// R28: prep_w dispatch (144 blocks) writes the FINAL fragment layout to d_ws
// (linear order == LDS layout: chunk c = f/8 = t*512+kc*256+n*64+l), then
// conv copies it via 9x global_load_lds dwordx4/thread — zero VALU, zero
// VGPR, zero scatter. Image staging / K-loop / stores = R25 verbatim.
// (R28-R30 benches lost to an unresponsive container; resubmitted unchanged.)
// ---------------------------------------------------------------------------

typedef _Float16 f16x8 __attribute__((ext_vector_type(8)));
typedef float    f32x4 __attribute__((ext_vector_type(4)));

#define NB 16
#define NC 64
#define NH 64
#define NW 64
#define CHUNKS 528                 // 66 xp positions * 8 channel-chunks per slab
#define SLAB_BYTES (CHUNKS * 16)   // 8448 B per image row slab
#define IMG_LDS (6 * SLAB_BYTES)   // 50,688 B
#define WF_HALFS (9 * 2 * 4 * 64 * 8)  // 36,864 halfs = 73,728 B = 4608 chunks

typedef __attribute__((address_space(3))) unsigned int lds_u32;
typedef __attribute__((address_space(1))) const unsigned int gbl_u32;

// ---------------------------------------------------------------------------
// prep_w: filts [1][inC][outC][3][3][2] f32 -> per-fragment f16 weights.
//   wf[f], f = t*4096 + kc*2048 + n*512 + l*8 + e  (= chunk c*8+e with
//   c = ((t*2+kc)*4+n)*64 + l — exactly conv's LDS layout, linear).
// ---------------------------------------------------------------------------
__global__ __launch_bounds__(256) void prep_w(const float* __restrict__ filts,
                                              _Float16* __restrict__ wf) {
    const int f = blockIdx.x * 256 + threadIdx.x;
    if (f >= WF_HALFS) return;
    const int e  = f & 7;
    const int l  = (f >> 3) & 63;
    const int n  = (f >> 9) & 3;
    const int kc = (f >> 11) & 1;
    const int t  = f >> 12;              // 0..8
    const int i  = kc * 32 + (l >> 4) * 8 + e;
    const int o  = n * 16 + (l & 15);
    const int ky = t / 3, kx = t % 3;
    wf[f] = (_Float16)filts[(((i * 64 + o) * 3 + ky) * 3 + kx) * 2];
}

// ---------------------------------------------------------------------------
// conv_one: 256 blocks (XCD-swizzled) = (b, 4-row quad), 8 waves (512 thr).
//   LDS: [0, 50688) image (6 slabs, swizzled chunks); [50688, 124416) wf.
//   Phase A: pads (tid<96) + image 48 jobs (R25 verbatim) + wf copy via
//     9 global_load_lds dwordx4/thread (chunk c = tid + 512j; wave-uniform
//     LDS base wfl+(j*512+w*64)*16, per-lane global src — zero VALU).
//   Phase B (R25 verbatim): wave w = (row w>>1, xh w&1), 32x x 64o tile,
//     per (ky,kx,kc): 2 A ds_reads + 4 B ds_reads + 8 MFMA.
//   C/D layout (m89/m91-verified): o = n*16+(lane&15), x = m*16+(lane>>4)*4+j
// ---------------------------------------------------------------------------
__global__ __launch_bounds__(512, 1) void conv_one(const float* __restrict__ imgs,
                                                   const _Float16* __restrict__ wfb,
                                                   float* __restrict__ out) {
    __shared__ char lds[IMG_LDS + WF_HALFS * 2];   // 124,416 B
    char* wfl = lds + IMG_LDS;
    const int bid = blockIdx.x;
    const int swz = ((bid & 7) << 5) | (bid >> 3);   // bijective: 256 = 8*32
    const int b   = swz >> 4;
    const int y0  = (swz & 15) << 2;     // first of 4 output rows
    const int tid = threadIdx.x;
    const int w   = tid >> 6;            // wave 0..7
    const int l   = tid & 63;
    const int h   = l >> 4;              // k-chunk lane group
    const int r   = l & 15;              // A-row / B-col within fragment

    // ---- wf: 9 DMA copies/thread, d_ws -> LDS (layout-preserving) ----
    {
        const char* g = reinterpret_cast<const char*>(wfb);
        #pragma unroll
        for (int j = 0; j < 9; ++j) {
            const int cbase = j * 512 + w * 64;          // wave-uniform chunk base
            __builtin_amdgcn_global_load_lds(
                (gbl_u32*)(g + (size_t)(cbase + l) * 16),
                (lds_u32*)(wfl + (size_t)cbase * 16), 16, 0, 0);
        }
    }

    // ---- pads: 6 slabs x 16 chunks (xp = 0, 65) ----
    if (tid < 96) {
        const int sl  = tid >> 4;
        const int rem = tid & 15;
        const int ci  = rem >> 1;
        const int xp2 = (rem & 1) ? 65 : 0;
        const int c2  = xp2 * 8 + (ci ^ (xp2 & 7));
        f16x8 z;
        #pragma unroll
        for (int k = 0; k < 8; ++k) z[k] = (_Float16)0.f;
        *reinterpret_cast<f16x8*>(lds + sl * SLAB_BYTES + c2 * 16) = z;
    }

    // ---- image: stage 6 slabs (rows y0-1 .. y0+4), 48 jobs over 8 waves ----
    #pragma unroll
    for (int j = 0; j < 6; ++j) {
        const int job = w + j * 8;
        const int sl  = job >> 3;
        const int ci  = job & 7;
        const int yy  = y0 - 1 + sl;
        float fr[8];
        if ((unsigned)yy < (unsigned)NH) {
            const float* src = imgs + (((size_t)(b * NC + ci * 8)) * NH + yy) * NW + l;
            #pragma unroll
            for (int k = 0; k < 8; ++k) fr[k] = src[(size_t)k * NH * NW];
        } else {
            #pragma unroll
            for (int k = 0; k < 8; ++k) fr[k] = 0.f;
        }
        f16x8 v;
        #pragma unroll
        for (int k = 0; k < 8; ++k) v[k] = (_Float16)fr[k];
        const int xp = l + 1;
        const int chunk = xp * 8 + (ci ^ (xp & 7));
        *reinterpret_cast<f16x8*>(lds + sl * SLAB_BYTES + chunk * 16) = v;
    }
    __syncthreads();

    const int row = w >> 1;              // output row within quad (0..3)
    const int xh  = w & 1;               // x half (0..1)

    f32x4 acc[2][4];
    #pragma unroll
    for (int m = 0; m < 2; ++m)
        #pragma unroll
        for (int n = 0; n < 4; ++n)
            acc[m][n] = f32x4{0.f, 0.f, 0.f, 0.f};

    #pragma unroll
    for (int ky = 0; ky < 3; ++ky) {
        const char* slab = lds + (row + 2 - ky) * SLAB_BYTES;   // sl in 0..5
        #pragma unroll
        for (int kx = 0; kx < 3; ++kx) {
            const int t = ky * 3 + kx;
            const char* wt = wfl + (size_t)t * 8192;   // 512 chunks * 16B per tap
            #pragma unroll
            for (int kc = 0; kc < 2; ++kc) {
                f16x8 a[2], bb[4];
                #pragma unroll
                for (int m = 0; m < 2; ++m) {
                    const int xp = xh * 32 + m * 16 + r + 2 - kx;  // 0..65
                    const int chunk = xp * 8 + (((kc << 2) + h) ^ (xp & 7));
                    a[m] = *reinterpret_cast<const f16x8*>(slab + chunk * 16);
                }
                #pragma unroll
                for (int n = 0; n < 4; ++n)
                    bb[n] = *reinterpret_cast<const f16x8*>(
                        wt + (size_t)(kc * 4 + n) * 1024 + l * 16);
                #pragma unroll
                for (int m = 0; m < 2; ++m)
                    #pragma unroll
                    for (int n = 0; n < 4; ++n)
                        acc[m][n] = __builtin_amdgcn_mfma_f32_16x16x32_f16(a[m], bb[n], acc[m][n], 0, 0, 0);
            }
        }
    }

    const int y = y0 + row;
    #pragma unroll
    for (int m = 0; m < 2; ++m) {
        const int x0 = xh * 32 + m * 16 + h * 4;
        #pragma unroll
        for (int n = 0; n < 4; ++n) {
            const int o = n * 16 + r;
            *reinterpret_cast<f32x4*>(out + (((size_t)(b * 64 + o) * 64 + y) * 64) + x0) = acc[m][n];
        }
    }
}

extern "C" void kernel_launch(void* const* d_in, const int* in_sizes, int n_in,
                              void* d_out, int out_size, void* d_ws, size_t ws_size,
                              hipStream_t stream) {
    const float* imgs  = (const float*)d_in[0];   // [16][64][64][64] f32
    const float* filts = (const float*)d_in[1];   // [1][64][64][3][3][2] f32
    float* out = (float*)d_out;                   // [16][64][64][64] f32
    _Float16* wfb = (_Float16*)d_ws;              // 73,728 B only

    hipLaunchKernelGGL(prep_w, dim3((WF_HALFS + 255) / 256), dim3(256), 0, stream, filts, wfb);
    hipLaunchKernelGGL(conv_one, dim3(256), dim3(512), 0, stream, imgs, wfb, out);
}